// Round 13
// baseline (760.410 us; speedup 1.0000x reference)
//
#include <hip/hip_runtime.h>
#include <math.h>

#define T  1024
#define PS 1156                    // 34*34 plane

#define ZSZ (4 * 5 * 1024 * 4)     // Z[quad g][j][pix] as float4 (floats)
// fcwT at ws + ZSZ: 8192 float4. total ws = 448 KB

// ---- scalar conv accumulate (prep + conv1; known-good 32-VGPR codegen) ----
template <int NIC, int NOC, int WSTR>
__device__ __forceinline__ void conv_acc(const float* __restrict__ ib,
                                         const float* __restrict__ wg,
                                         float* __restrict__ acc) {
#pragma unroll 2
    for (int ic = 0; ic < NIC; ++ic) {
        float v[9];
#pragma unroll
        for (int ky = 0; ky < 3; ++ky)
#pragma unroll
            for (int kx = 0; kx < 3; ++kx)
                v[ky * 3 + kx] = ib[ic * PS + ky * 34 + kx];
#pragma unroll
        for (int oc = 0; oc < NOC; ++oc) {
            const float* wp = wg + oc * WSTR + ic * 9;
#pragma unroll
            for (int k = 0; k < 9; ++k)
                acc[oc] = fmaf(wp[k], v[k], acc[oc]);
        }
    }
}

// ---- ONE-LIVE channel-quad conv: per (ky,kx) load a single float4 (4 input
// channels) and fold into acc. Live regs = 4 (r) + acc[NOC] — fits the
// 32-VGPR pin that LB(1024,8) enforces. 9 b128 reads per quad plane.
template <int NOC, int WSTR>
__device__ __forceinline__ void conv_q1(const float4* __restrict__ ib,
                                        const float* __restrict__ wg,
                                        float* __restrict__ acc) {
#pragma unroll
    for (int ky = 0; ky < 3; ++ky) {
#pragma unroll
        for (int kx = 0; kx < 3; ++kx) {
            const float4 r = ib[ky * 34 + kx];
            const float* wk = wg + ky * 3 + kx;   // uniform -> s_load
#pragma unroll
            for (int oc = 0; oc < NOC; ++oc) {
                const float* wp = wk + oc * WSTR;
                acc[oc] = fmaf(wp[0], r.x,
                          fmaf(wp[9], r.y,
                          fmaf(wp[18], r.z,
                          fmaf(wp[27], r.w, acc[oc]))));
            }
        }
        __builtin_amdgcn_sched_barrier(0);   // keep one row-group's loads local
    }
}

// ---- prep 1: decoder basis Z[g][j][pix] = conv3x3(F_j, d1w) (+d1b for j=4) ----
__global__ __launch_bounds__(T) void prep_z_kernel(
    const float* __restrict__ f2w, const float* __restrict__ f2b,
    const float* __restrict__ d1w, const float* __restrict__ d1b,
    float* __restrict__ ws) {
    __shared__ float F[8 * PS];
    const int tid = threadIdx.x;
    const int j = blockIdx.x;                 // 0..4 (4 = bias basis)
    const int py = tid >> 5, px = tid & 31;
    const int wbase = py * 34 + px;
    const int ibase = (py + 1) * 34 + (px + 1);

    for (int i = tid; i < 8 * PS; i += T) F[i] = 0.f;
    __syncthreads();
#pragma unroll
    for (int c = 0; c < 8; ++c) {
        const int idx = c * 1024 + tid;
        F[c * PS + ibase] = (j < 4) ? f2w[idx * 4 + j] : f2b[idx];
    }
    __syncthreads();
    float a1[16];
#pragma unroll
    for (int oc = 0; oc < 16; ++oc) a1[oc] = (j == 4) ? d1b[oc] : 0.f;
    conv_acc<8, 16, 72>(F + wbase, d1w, a1);
#pragma unroll
    for (int g = 0; g < 4; ++g) {
        float4 v = make_float4(a1[4 * g], a1[4 * g + 1], a1[4 * g + 2], a1[4 * g + 3]);
        *reinterpret_cast<float4*>(ws + ((g * 5 + j) * 1024 + tid) * 4) = v;
    }
}

// ---- prep 2: fcwT[gj] = float4{fcw[o*8192+gj]} ----
__global__ __launch_bounds__(T) void prep_fcwt_kernel(
    const float* __restrict__ fcw, float* __restrict__ fcwT) {
    const int i = blockIdx.x * T + threadIdx.x;
#pragma unroll
    for (int o = 0; o < 4; ++o)
        fcwT[i * 4 + o] = fcw[o * 8192 + i];
}

// ---------------- fused per-image kernel -----------------------------------
// Exactly R6 (181.5us anchor) except: (a) BQ planes are float4 channel-quads,
// conv2/dconv2 read them via conv_q1 (36 b128/px instead of 144 b32/px);
// (b) fc final reduce parallelized (shuffle tree, angles broadcast by shfl).
// conv1 unchanged (scalar LDS reads, the proven 32-VGPR body).
// LDS: XS 13.9KB + BQ 37KB + SM 0.7KB = 51.5KB -> 2 blocks/CU.
__global__ __launch_bounds__(T, 8) void fused_kernel(
    const float* __restrict__ x,
    const float* __restrict__ c1w, const float* __restrict__ c1b,
    const float* __restrict__ c2w, const float* __restrict__ c2b,
    const float* __restrict__ fcb,
    const float* __restrict__ qw,
    const float* __restrict__ d2w, const float* __restrict__ d2b,
    const float* __restrict__ ws,
    float* __restrict__ out) {
    __shared__ float  XS[3 * PS];     // x scalar planes (conv1 input)
    __shared__ float4 BQ[2 * PS];     // activation channel-quad planes
    __shared__ float  SM[168];        // ROT 96 | ANG 4 | Q 4 | RED 64
    float* ROT = SM;
    const float* fcwT = ws + ZSZ;

    const int tid = threadIdx.x;
    const int b   = blockIdx.x;
    const int py  = tid >> 5, px = tid & 31;
    const int wbase = py * 34 + px;
    const int ibase = (py + 1) * 34 + (px + 1);

    const float4 z4 = make_float4(0.f, 0.f, 0.f, 0.f);
    for (int i = tid; i < 3 * PS; i += T) XS[i] = 0.f;      // halos must be 0
    for (int i = tid; i < 2 * PS; i += T) BQ[i] = z4;
    if (tid < 168) SM[tid] = 0.f;
    __syncthreads();

    if (tid < 12) {   // Rot matrices (batch-independent, tiny)
        float phi = qw[tid * 3 + 0], theta = qw[tid * 3 + 1], omega = qw[tid * 3 + 2];
        float a = 0.5f * (phi + omega), d = 0.5f * (phi - omega);
        float st, ct; sincosf(0.5f * theta, &st, &ct);
        float sa, ca; sincosf(a, &sa, &ca);
        float sd, cd; sincosf(d, &sd, &cd);
        float* o = ROT + tid * 8;
        o[0] = ct * ca;  o[1] = -ct * sa;
        o[2] = -st * cd; o[3] = -st * sd;
        o[4] = st * cd;  o[5] = -st * sd;
        o[6] = ct * ca;  o[7] = ct * sa;
    }

    // ---- load x (3,32,32) into XS interior ----
    {
        const float* xb = x + b * 3072;
#pragma unroll
        for (int k = 0; k < 3; ++k) {
            int i = tid + k * T;
            int c = i >> 10, p = i & 1023;
            XS[c * PS + ((p >> 5) + 1) * 34 + (p & 31) + 1] = xb[i];
        }
    }
    __syncthreads();

    float acc2[8];
#pragma unroll
    for (int oc = 0; oc < 8; ++oc) acc2[oc] = c2b[oc];
    float part[4] = {0.f, 0.f, 0.f, 0.f};

#pragma unroll
    for (int h = 0; h < 2; ++h) {
        // ---- conv1 half h (oc h*8..h*8+7): scalar LDS body -> quad planes ----
        {
            float a1[8];
#pragma unroll
            for (int oc = 0; oc < 8; ++oc) a1[oc] = c1b[h * 8 + oc];
            conv_acc<3, 8, 27>(XS + wbase, c1w + h * 8 * 27, a1);
            BQ[ibase]      = make_float4(fmaxf(a1[0], 0.f), fmaxf(a1[1], 0.f),
                                         fmaxf(a1[2], 0.f), fmaxf(a1[3], 0.f));
            BQ[PS + ibase] = make_float4(fmaxf(a1[4], 0.f), fmaxf(a1[5], 0.f),
                                         fmaxf(a1[6], 0.f), fmaxf(a1[7], 0.f));
        }
        __syncthreads();
        // ---- conv2 partial over this half's 8 input channels (2 quad planes) ----
        conv_q1<8, 144>(BQ + wbase,      c2w + (h * 8 + 0) * 9, acc2);
        conv_q1<8, 144>(BQ + PS + wbase, c2w + (h * 8 + 4) * 9, acc2);
        __syncthreads();   // before next half overwrites BQ
    }

    // ---- relu + fc fold (float4 fcwT) ----
#pragma unroll
    for (int oc = 0; oc < 8; ++oc) {
        const float hv = fmaxf(acc2[oc], 0.f);
        const float4 wv = *reinterpret_cast<const float4*>(fcwT + (oc * 1024 + tid) * 4);
        part[0] = fmaf(hv, wv.x, part[0]);
        part[1] = fmaf(hv, wv.y, part[1]);
        part[2] = fmaf(hv, wv.z, part[2]);
        part[3] = fmaf(hv, wv.w, part[3]);
    }

    // ---- fc reduce: wave-level, then 64-lane tree (no serial tid0 loop) ----
#pragma unroll
    for (int off = 32; off; off >>= 1)
#pragma unroll
        for (int o = 0; o < 4; ++o)
            part[o] += __shfl_down(part[o], off);
    if ((tid & 63) == 0) {
        int wid = tid >> 6;
#pragma unroll
        for (int o = 0; o < 4; ++o) SM[104 + wid * 4 + o] = part[o];
    }
    __syncthreads();

    // ---- angles + 4-qubit statevector sim (wave 0 only) ----
    if (tid < 64) {
        // parallel final reduce: SM[104+tid] holds partial (wid*4+o == tid)
        float v = SM[104 + tid];
#pragma unroll
        for (int m = 4; m < 64; m <<= 1) v += __shfl_down(v, m);
        float ang = (tid < 4) ? (fcb[tid] + v) : 0.f;   // lanes 0..3 valid

        const int s = tid & 15;
        float re = (s == 0) ? 1.f : 0.f, im = 0.f;
#pragma unroll
        for (int w = 0; w < 4; ++w) {
            float a = __shfl(ang, w) * 0.5f;
            float sn, c; sincosf(a, &sn, &c);
            int stride = 1 << (3 - w);
            float pr = __shfl_xor(re, stride);
            float pi = __shfl_xor(im, stride);
            float nre = c * re + sn * pi;
            float nim = c * im - sn * pr;
            re = nre; im = nim;
        }
#pragma unroll
        for (int l = 0; l < 3; ++l) {
#pragma unroll
            for (int w = 0; w < 4; ++w) {
                const float* U = ROT + (l * 4 + w) * 8;
                int stride = 1 << (3 - w);
                bool bit = (s & stride) != 0;
                float pr = __shfl_xor(re, stride);
                float pi = __shfl_xor(im, stride);
                float cAr = bit ? U[6] : U[0], cAi = bit ? U[7] : U[1];
                float cBr = bit ? U[4] : U[2], cBi = bit ? U[5] : U[3];
                float nre = cAr * re - cAi * im + cBr * pr - cBi * pi;
                float nim = cAr * im + cAi * re + cBr * pi + cBi * pr;
                re = nre; im = nim;
            }
            const int r = (l % 3) + 1;
#pragma unroll
            for (int w = 0; w < 4; ++w) {
                int cs = 1 << (3 - w);
                int ts = 1 << (3 - ((w + r) & 3));
                float pr = __shfl_xor(re, ts);
                float pi = __shfl_xor(im, ts);
                if (s & cs) { re = pr; im = pi; }
            }
        }
        float pprob = re * re + im * im;
        float ev[4];
#pragma unroll
        for (int w = 0; w < 4; ++w)
            ev[w] = (s & (1 << (3 - w))) ? -pprob : pprob;
#pragma unroll
        for (int m = 1; m <= 8; m <<= 1)
#pragma unroll
            for (int w = 0; w < 4; ++w)
                ev[w] += __shfl_xor(ev[w], m);
        if (tid == 0) {
#pragma unroll
            for (int w = 0; w < 4; ++w) SM[100 + w] = ev[w];
        }
    }
    __syncthreads();

    const float qv[5] = {SM[100], SM[101], SM[102], SM[103], 1.f};

    // ---- decoder: h4 quad halves from rank-5 basis, dconv2 partials ----
    float acc3[3];
#pragma unroll
    for (int oc = 0; oc < 3; ++oc) acc3[oc] = d2b[oc];

#pragma unroll
    for (int h = 0; h < 2; ++h) {
#pragma unroll
        for (int gg = 0; gg < 2; ++gg) {
            const int g = h * 2 + gg;       // quad g covers channels 4g..4g+3
            float4 a = z4;
#pragma unroll
            for (int j = 0; j < 5; ++j) {
                const float4 zv = *reinterpret_cast<const float4*>(
                    ws + ((g * 5 + j) * 1024 + tid) * 4);
                a.x = fmaf(qv[j], zv.x, a.x);
                a.y = fmaf(qv[j], zv.y, a.y);
                a.z = fmaf(qv[j], zv.z, a.z);
                a.w = fmaf(qv[j], zv.w, a.w);
            }
            BQ[gg * PS + ibase] = make_float4(fmaxf(a.x, 0.f), fmaxf(a.y, 0.f),
                                              fmaxf(a.z, 0.f), fmaxf(a.w, 0.f));
        }
        __syncthreads();
        conv_q1<3, 144>(BQ + wbase,      d2w + (h * 8 + 0) * 9, acc3);
        conv_q1<3, 144>(BQ + PS + wbase, d2w + (h * 8 + 4) * 9, acc3);
        if (h == 0) __syncthreads();   // protect half1's BQ overwrite
    }

    // ---- sigmoid -> out ----
    {
        float* ob = out + b * 3072 + tid;
#pragma unroll
        for (int oc = 0; oc < 3; ++oc)
            ob[oc * 1024] = 1.f / (1.f + expf(-acc3[oc]));
    }
}

// ---------------- launch ----------------------------------------------------
extern "C" void kernel_launch(void* const* d_in, const int* in_sizes, int n_in,
                              void* d_out, int out_size, void* d_ws, size_t ws_size,
                              hipStream_t stream) {
    const float* x   = (const float*)d_in[0];
    const float* c1w = (const float*)d_in[1];
    const float* c1b = (const float*)d_in[2];
    const float* c2w = (const float*)d_in[3];
    const float* c2b = (const float*)d_in[4];
    const float* fcw = (const float*)d_in[5];
    const float* fcb = (const float*)d_in[6];
    const float* qw  = (const float*)d_in[7];
    const float* f2w = (const float*)d_in[8];
    const float* f2b = (const float*)d_in[9];
    const float* d1w = (const float*)d_in[10];
    const float* d1b = (const float*)d_in[11];
    const float* d2w = (const float*)d_in[12];
    const float* d2b = (const float*)d_in[13];
    float* out = (float*)d_out;
    float* ws  = (float*)d_ws;

    prep_z_kernel<<<5, T, 0, stream>>>(f2w, f2b, d1w, d1b, ws);
    prep_fcwt_kernel<<<8, T, 0, stream>>>(fcw, ws + ZSZ);
    fused_kernel<<<2048, T, 0, stream>>>(
        x, c1w, c1b, c2w, c2b, fcb, qw, d2w, d2b, ws, out);
}

// Round 14
// 181.668 us; speedup vs baseline: 4.1857x; 4.1857x over previous
//
#include <hip/hip_runtime.h>
#include <math.h>

#define T 1024
#define PS 1156                    // 34*34 plane
#define OFF_B   (3 * PS)           // planes 3..10: conv1/h4 halves (8 planes)
#define OFF_ROT (11 * PS)          // 96
#define OFF_ANG (OFF_ROT + 96)
#define OFF_Q   (OFF_ANG + 4)
#define OFF_RED (OFF_Q + 4)        // 64
#define LDS_FLOATS (OFF_RED + 64)  // 12884 floats = 51536 B -> 2 blocks/CU

#define ZSZ (4 * 5 * 1024 * 4)     // 81920 floats: Z[quad g][j][pix] as float4
// fcwT lives at ws + ZSZ: 8192 float4 (32768 floats). total ws = 448 KB

// scalar 3x3 conv accumulate (known-good codegen: ds_read_b32 + uniform s_load)
template <int NIC, int NOC, int WSTR>
__device__ __forceinline__ void conv_acc(const float* __restrict__ ib,
                                         const float* __restrict__ wg,
                                         float* __restrict__ acc) {
#pragma unroll 2
    for (int ic = 0; ic < NIC; ++ic) {
        float v[9];
#pragma unroll
        for (int ky = 0; ky < 3; ++ky)
#pragma unroll
            for (int kx = 0; kx < 3; ++kx)
                v[ky * 3 + kx] = ib[ic * PS + ky * 34 + kx];
#pragma unroll
        for (int oc = 0; oc < NOC; ++oc) {
            const float* wp = wg + oc * WSTR + ic * 9;
#pragma unroll
            for (int k = 0; k < 9; ++k)
                acc[oc] = fmaf(wp[k], v[k], acc[oc]);
        }
    }
}

// ---- prep 1: decoder basis Z[g][j][pix] = conv3x3(F_j, d1w) (+d1b for j=4) ----
__global__ __launch_bounds__(T) void prep_z_kernel(
    const float* __restrict__ f2w, const float* __restrict__ f2b,
    const float* __restrict__ d1w, const float* __restrict__ d1b,
    float* __restrict__ ws) {
    __shared__ float F[8 * PS];
    const int tid = threadIdx.x;
    const int j = blockIdx.x;                 // 0..4 (4 = bias basis)
    const int py = tid >> 5, px = tid & 31;
    const int wbase = py * 34 + px;
    const int ibase = (py + 1) * 34 + (px + 1);

    for (int i = tid; i < 8 * PS; i += T) F[i] = 0.f;
    __syncthreads();
#pragma unroll
    for (int c = 0; c < 8; ++c) {
        const int idx = c * 1024 + tid;
        F[c * PS + ibase] = (j < 4) ? f2w[idx * 4 + j] : f2b[idx];
    }
    __syncthreads();
    float a1[16];
#pragma unroll
    for (int oc = 0; oc < 16; ++oc) a1[oc] = (j == 4) ? d1b[oc] : 0.f;
    conv_acc<8, 16, 72>(F + wbase, d1w, a1);
#pragma unroll
    for (int g = 0; g < 4; ++g) {
        float4 v = make_float4(a1[4 * g], a1[4 * g + 1], a1[4 * g + 2], a1[4 * g + 3]);
        *reinterpret_cast<float4*>(ws + ((g * 5 + j) * 1024 + tid) * 4) = v;
    }
}

// ---- prep 2: fcwT[gj] = float4{fcw[o*8192+gj]} ----
__global__ __launch_bounds__(T) void prep_fcwt_kernel(
    const float* __restrict__ fcw, float* __restrict__ fcwT) {
    const int i = blockIdx.x * T + threadIdx.x;   // 0..8191
#pragma unroll
    for (int o = 0; o < 4; ++o)
        fcwT[i * 4 + o] = fcw[o * 8192 + i];
}

// ---------------- fused per-image kernel (R6 anchor + parallel fc reduce) ----
__global__ __launch_bounds__(T, 8) void fused_kernel(
    const float* __restrict__ x,
    const float* __restrict__ c1w, const float* __restrict__ c1b,
    const float* __restrict__ c2w, const float* __restrict__ c2b,
    const float* __restrict__ fcb,
    const float* __restrict__ qw,
    const float* __restrict__ d2w, const float* __restrict__ d2b,
    const float* __restrict__ ws,     // Z basis + fcwT
    float* __restrict__ out) {
    __shared__ float lds[LDS_FLOATS];
    float* A   = lds;            // 3 planes: x
    float* Bf  = lds + OFF_B;    // 8 planes: conv1 halves / h4 halves
    float* ROT = lds + OFF_ROT;
    const float* fcwT = ws + ZSZ;

    const int tid = threadIdx.x;
    const int b   = blockIdx.x;
    const int py  = tid >> 5, px = tid & 31;
    const int wbase = py * 34 + px;
    const int ibase = (py + 1) * 34 + (px + 1);

    for (int i = tid; i < LDS_FLOATS; i += T) lds[i] = 0.f;   // halos must be 0
    __syncthreads();

    if (tid < 12) {   // Rot matrices (batch-independent, tiny)
        float phi = qw[tid * 3 + 0], theta = qw[tid * 3 + 1], omega = qw[tid * 3 + 2];
        float a = 0.5f * (phi + omega), d = 0.5f * (phi - omega);
        float st, ct; sincosf(0.5f * theta, &st, &ct);
        float sa, ca; sincosf(a, &sa, &ca);
        float sd, cd; sincosf(d, &sd, &cd);
        float* o = ROT + tid * 8;
        o[0] = ct * ca;  o[1] = -ct * sa;
        o[2] = -st * cd; o[3] = -st * sd;
        o[4] = st * cd;  o[5] = -st * sd;
        o[6] = ct * ca;  o[7] = ct * sa;
    }

    // ---- load x (3,32,32) into A interior ----
    const float* xb = x + b * 3072;
#pragma unroll
    for (int k = 0; k < 3; ++k) {
        int i = tid + k * T;
        int c = i >> 10, p = i & 1023;
        A[c * PS + ((p >> 5) + 1) * 34 + (p & 31) + 1] = xb[i];
    }
    __syncthreads();

    float acc2[8];
#pragma unroll
    for (int oc = 0; oc < 8; ++oc) acc2[oc] = c2b[oc];
    float part[4] = {0.f, 0.f, 0.f, 0.f};

    // ---- conv1 half0 (oc 0..7) -> B ----
    {
        float a1[8];
#pragma unroll
        for (int oc = 0; oc < 8; ++oc) a1[oc] = c1b[oc];
        conv_acc<3, 8, 27>(A + wbase, c1w, a1);
#pragma unroll
        for (int oc = 0; oc < 8; ++oc) Bf[oc * PS + ibase] = fmaxf(a1[oc], 0.f);
    }
    __syncthreads();
    conv_acc<8, 8, 144>(Bf + wbase, c2w, acc2);          // conv2 partial ic 0..7
    __syncthreads();
    // ---- conv1 half1 (oc 8..15) -> B ----
    {
        float a1[8];
#pragma unroll
        for (int oc = 0; oc < 8; ++oc) a1[oc] = c1b[8 + oc];
        conv_acc<3, 8, 27>(A + wbase, c1w + 8 * 27, a1);
#pragma unroll
        for (int oc = 0; oc < 8; ++oc) Bf[oc * PS + ibase] = fmaxf(a1[oc], 0.f);
    }
    __syncthreads();
    conv_acc<8, 8, 144>(Bf + wbase, c2w + 8 * 9, acc2);  // conv2 partial ic 8..15
    // ---- relu + fc fold (float4 fcwT) ----
#pragma unroll
    for (int oc = 0; oc < 8; ++oc) {
        const float h = fmaxf(acc2[oc], 0.f);
        const float4 wv = *reinterpret_cast<const float4*>(fcwT + (oc * 1024 + tid) * 4);
        part[0] = fmaf(h, wv.x, part[0]);
        part[1] = fmaf(h, wv.y, part[1]);
        part[2] = fmaf(h, wv.z, part[2]);
        part[3] = fmaf(h, wv.w, part[3]);
    }

    // ---- fc reduce: wave tree -> LDS -> lane-parallel final (no serial tid0) ----
#pragma unroll
    for (int off = 32; off; off >>= 1)
#pragma unroll
        for (int o = 0; o < 4; ++o)
            part[o] += __shfl_down(part[o], off);
    if ((tid & 63) == 0) {
        int wid = tid >> 6;
#pragma unroll
        for (int o = 0; o < 4; ++o) lds[OFF_RED + wid * 4 + o] = part[o];
    }
    __syncthreads();

    // ---- angles + 4-qubit statevector sim (wave 0 only) ----
    if (tid < 64) {
        // lane-parallel final reduce: lds[OFF_RED + tid] = partial(wid=tid>>2, o=tid&3)
        float v = lds[OFF_RED + tid];
#pragma unroll
        for (int m = 4; m < 64; m <<= 1) v += __shfl_down(v, m);
        float ang = (tid < 4) ? (fcb[tid] + v) : 0.f;   // lanes 0..3 hold angles

        const int s = tid & 15;
        float re = (s == 0) ? 1.f : 0.f, im = 0.f;
#pragma unroll
        for (int w = 0; w < 4; ++w) {
            float a = __shfl(ang, w) * 0.5f;
            float sn, c; sincosf(a, &sn, &c);
            int stride = 1 << (3 - w);
            float pr = __shfl_xor(re, stride);
            float pi = __shfl_xor(im, stride);
            float nre = c * re + sn * pi;
            float nim = c * im - sn * pr;
            re = nre; im = nim;
        }
#pragma unroll
        for (int l = 0; l < 3; ++l) {
#pragma unroll
            for (int w = 0; w < 4; ++w) {
                const float* U = ROT + (l * 4 + w) * 8;
                int stride = 1 << (3 - w);
                bool bit = (s & stride) != 0;
                float pr = __shfl_xor(re, stride);
                float pi = __shfl_xor(im, stride);
                float cAr = bit ? U[6] : U[0], cAi = bit ? U[7] : U[1];
                float cBr = bit ? U[4] : U[2], cBi = bit ? U[5] : U[3];
                float nre = cAr * re - cAi * im + cBr * pr - cBi * pi;
                float nim = cAr * im + cAi * re + cBr * pi + cBi * pr;
                re = nre; im = nim;
            }
            const int r = (l % 3) + 1;
#pragma unroll
            for (int w = 0; w < 4; ++w) {
                int cs = 1 << (3 - w);
                int ts = 1 << (3 - ((w + r) & 3));
                float pr = __shfl_xor(re, ts);
                float pi = __shfl_xor(im, ts);
                if (s & cs) { re = pr; im = pi; }
            }
        }
        float pprob = re * re + im * im;
        float ev[4];
#pragma unroll
        for (int w = 0; w < 4; ++w)
            ev[w] = (s & (1 << (3 - w))) ? -pprob : pprob;
#pragma unroll
        for (int m = 1; m <= 8; m <<= 1)
#pragma unroll
            for (int w = 0; w < 4; ++w)
                ev[w] += __shfl_xor(ev[w], m);
        if (tid == 0) {
#pragma unroll
            for (int w = 0; w < 4; ++w) lds[OFF_Q + w] = ev[w];
        }
    }
    __syncthreads();

    const float qv[5] = {lds[OFF_Q + 0], lds[OFF_Q + 1],
                         lds[OFF_Q + 2], lds[OFF_Q + 3], 1.f};

    // ---- decoder: h4 halves from rank-5 basis, dconv2 partials ----
    float acc3[3];
#pragma unroll
    for (int oc = 0; oc < 3; ++oc) acc3[oc] = d2b[oc];

#pragma unroll
    for (int h = 0; h < 2; ++h) {
#pragma unroll
        for (int gg = 0; gg < 2; ++gg) {
            const int g = h * 2 + gg;
            float4 a = make_float4(0.f, 0.f, 0.f, 0.f);
#pragma unroll
            for (int j = 0; j < 5; ++j) {
                const float4 zv = *reinterpret_cast<const float4*>(
                    ws + ((g * 5 + j) * 1024 + tid) * 4);
                a.x = fmaf(qv[j], zv.x, a.x);
                a.y = fmaf(qv[j], zv.y, a.y);
                a.z = fmaf(qv[j], zv.z, a.z);
                a.w = fmaf(qv[j], zv.w, a.w);
            }
            Bf[(gg * 4 + 0) * PS + ibase] = fmaxf(a.x, 0.f);
            Bf[(gg * 4 + 1) * PS + ibase] = fmaxf(a.y, 0.f);
            Bf[(gg * 4 + 2) * PS + ibase] = fmaxf(a.z, 0.f);
            Bf[(gg * 4 + 3) * PS + ibase] = fmaxf(a.w, 0.f);
        }
        __syncthreads();
        conv_acc<8, 3, 144>(Bf + wbase, d2w + h * 72, acc3);
        if (h == 0) __syncthreads();   // protect half1's B overwrite
    }

    // ---- sigmoid -> out ----
    {
        float* ob = out + b * 3072 + tid;
#pragma unroll
        for (int oc = 0; oc < 3; ++oc)
            ob[oc * 1024] = 1.f / (1.f + expf(-acc3[oc]));
    }
}

// ---------------- launch ----------------------------------------------------
extern "C" void kernel_launch(void* const* d_in, const int* in_sizes, int n_in,
                              void* d_out, int out_size, void* d_ws, size_t ws_size,
                              hipStream_t stream) {
    const float* x   = (const float*)d_in[0];
    const float* c1w = (const float*)d_in[1];
    const float* c1b = (const float*)d_in[2];
    const float* c2w = (const float*)d_in[3];
    const float* c2b = (const float*)d_in[4];
    const float* fcw = (const float*)d_in[5];
    const float* fcb = (const float*)d_in[6];
    const float* qw  = (const float*)d_in[7];
    const float* f2w = (const float*)d_in[8];
    const float* f2b = (const float*)d_in[9];
    const float* d1w = (const float*)d_in[10];
    const float* d1b = (const float*)d_in[11];
    const float* d2w = (const float*)d_in[12];
    const float* d2b = (const float*)d_in[13];
    float* out = (float*)d_out;
    float* ws  = (float*)d_ws;   // Z basis (81920 f) + fcwT (32768 f) = 448 KB

    prep_z_kernel<<<5, T, 0, stream>>>(f2w, f2b, d1w, d1b, ws);
    prep_fcwt_kernel<<<8, T, 0, stream>>>(fcw, ws + ZSZ);
    fused_kernel<<<2048, T, 0, stream>>>(
        x, c1w, c1b, c2w, c2b, fcb, qw, d2w, d2b, ws, out);
}